// Round 2
// baseline (32387.726 us; speedup 1.0000x reference)
//
#include <hip/hip_runtime.h>
#include <hip/hip_cooperative_groups.h>

namespace cg = cooperative_groups;

#define T_ 256
#define B_ 32
#define F_ 512
#define H_ 1024
#define O_ 512
#define KTOT 1536   // H + F
#define NCOL 4096   // 4 gates * H
#define KC 192      // K-chunk for recurrence LDS staging (8 chunks)

// ---------------------------------------------------------------------------
// ws layout (floats):
//   Wt    [4096][1536]  dense fused weight, col-major rows (K contiguous)
//   bsum  [4096]        bx+bh
//   hzero [64*1024]     zero initial h
//   hs    [256][64][1024] per-step hidden states
// ---------------------------------------------------------------------------
#define WT_OFF   0
#define BSUM_OFF (NCOL * KTOT)                 // 6291456
#define HZ_OFF   (BSUM_OFF + NCOL)            // 6295552
#define HS_OFF   (HZ_OFF + 64 * H_)           // 6361088
// total floats = HS_OFF + 256*64*1024 = 23138304  (~92.6 MB)

// Build dense Wt[c][k]:  c = g*1024 + q*256 + nn ; k<1024: h-part, k>=1024: x-part
__global__ void prep_w(const float* __restrict__ Wx, const float* __restrict__ Wh,
                       float* __restrict__ Wt) {
    int idx = blockIdx.x * 256 + threadIdx.x;   // over 4096*1536
    int c = idx / KTOT;
    int k = idx - c * KTOT;
    int g  = c >> 10;
    int n  = c & 1023;
    int q  = n >> 8;
    int nn = n & 255;
    // quaternion Hamilton tables: output comp q, input comp p
    const int   comp[4][4] = {{0,1,2,3},{1,0,3,2},{2,3,0,1},{3,2,1,0}};
    const float sgn [4][4] = {{1.f,-1.f,-1.f,-1.f},
                              {1.f, 1.f,-1.f, 1.f},
                              {1.f, 1.f, 1.f,-1.f},
                              {1.f,-1.f, 1.f, 1.f}};
    float v;
    if (k < H_) {
        int p = k >> 8, kk = k & 255;
        v = sgn[q][p] * Wh[((size_t)(g*4 + comp[q][p]) * 256 + kk) * 256 + nn];
    } else {
        int k2 = k - H_;
        int p = k2 >> 7, kk = k2 & 127;
        v = sgn[q][p] * Wx[((size_t)(g*4 + comp[q][p]) * 128 + kk) * 256 + nn];
    }
    Wt[idx] = v;
}

__global__ void prep_misc(const float* __restrict__ bx, const float* __restrict__ bh,
                          float* __restrict__ bsum, float* __restrict__ hzero) {
    int idx = blockIdx.x * 256 + threadIdx.x;
    if (idx < NCOL)    bsum[idx] = bx[idx] + bh[idx];  // flat (4,1024) == g*1024+n
    if (idx < 64 * H_) hzero[idx] = 0.f;
}

// ---------------------------------------------------------------------------
// Cooperative recurrence: 256 wgs x 256 threads.
// wg owns 4 n-columns x 4 gates. thread (b = tid&63, j = tid>>6) owns (b, n=wg*4+j),
// computes all 4 gate pre-activations (K=1536 fused [h | x_t]) and updates c,h.
// ---------------------------------------------------------------------------
__global__ __launch_bounds__(256) void recur(
    const float* __restrict__ x, const float* __restrict__ Wt,
    const float* __restrict__ bsum, const float* __restrict__ hzero,
    float* __restrict__ hs) {
    __shared__ float A[64][KC + 4];   // [b][k] padded: stride 196 floats (16B-mult)
    const int tid = threadIdx.x;
    const int wg  = blockIdx.x;
    const int b   = tid & 63;
    const int j   = tid >> 6;
    const int n   = wg * 4 + j;
    const int col0 = n, col1 = H_ + n, col2 = 2 * H_ + n, col3 = 3 * H_ + n;
    const float4* __restrict__ Wt4 = (const float4*)Wt;
    const size_t r0 = (size_t)col0 * (KTOT / 4);
    const size_t r1 = (size_t)col1 * (KTOT / 4);
    const size_t r2 = (size_t)col2 * (KTOT / 4);
    const size_t r3 = (size_t)col3 * (KTOT / 4);

    float cst = 0.f;
    cg::grid_group grid = cg::this_grid();
    const float* hprev = hzero;

    for (int t = 0; t < T_; ++t) {
        float a0 = bsum[col0], a1 = bsum[col1], a2 = bsum[col2], a3 = bsum[col3];
        for (int kc = 0; kc < KTOT / KC; ++kc) {
            __syncthreads();
            // stage A chunk [64][KC] from h_prev and x_t
            for (int idx = tid; idx < 64 * (KC / 4); idx += 256) {
                int b2 = idx / (KC / 4);
                int q  = idx - b2 * (KC / 4);
                int kg = kc * KC + q * 4;
                float4 v;
                if (kg < H_) {
                    v = *(const float4*)(hprev + (size_t)b2 * H_ + kg);
                } else {
                    int kx = kg - H_;
                    const float* src = (b2 < B_)
                        ? (x + ((size_t)t * B_ + b2) * F_ + kx)
                        : (x + ((size_t)(T_ - 1 - t) * B_ + (b2 - B_)) * F_ + kx);
                    v = *(const float4*)src;
                }
                *(float4*)(&A[b2][q * 4]) = v;
            }
            __syncthreads();
            const int kb4 = (kc * KC) / 4;
            #pragma unroll 4
            for (int kl = 0; kl < KC; kl += 4) {
                float4 av = *(const float4*)(&A[b][kl]);
                float4 w0 = Wt4[r0 + kb4 + (kl >> 2)];
                float4 w1 = Wt4[r1 + kb4 + (kl >> 2)];
                float4 w2 = Wt4[r2 + kb4 + (kl >> 2)];
                float4 w3 = Wt4[r3 + kb4 + (kl >> 2)];
                a0 += av.x * w0.x + av.y * w0.y + av.z * w0.z + av.w * w0.w;
                a1 += av.x * w1.x + av.y * w1.y + av.z * w1.z + av.w * w1.w;
                a2 += av.x * w2.x + av.y * w2.y + av.z * w2.z + av.w * w2.w;
                a3 += av.x * w3.x + av.y * w3.y + av.z * w3.z + av.w * w3.w;
            }
        }
        // gate math (f, i, o, a)
        float ft = 1.f / (1.f + expf(-a0));
        float it = 1.f / (1.f + expf(-a1));
        float ot = 1.f / (1.f + expf(-a2));
        cst = it * tanhf(a3) + ft * cst;
        float h = ot * tanhf(cst);
        float* hcur = hs + (size_t)t * 64 * H_;
        hcur[(size_t)b * H_ + n] = h;
        grid.sync();
        hprev = hcur;
    }
}

// ---------------------------------------------------------------------------
// Final GEMM: out[t][b][o] = [h_f | h_b] @ fco_w + fco_b
//   rows (t,b): k<1024 -> hs[t][b][k] ; k>=1024 -> hs[255-t][32+b][k-1024]
// grid (8 col-groups of 64, 256 t), 256 threads, micro-tile 2b x 4c.
// ---------------------------------------------------------------------------
#define FKC 128
__global__ __launch_bounds__(256) void finalk(
    const float* __restrict__ hs, const float* __restrict__ fco_w,
    const float* __restrict__ fco_b, float* __restrict__ out) {
    __shared__ float Bl[FKC][68];
    __shared__ float Al[B_][FKC + 4];
    const int t  = blockIdx.y;
    const int c0 = blockIdx.x * 64;
    const int tid = threadIdx.x;
    const int tx = tid & 15;     // 4 cols: c0 + tx*4 + jc
    const int ty = tid >> 4;     // 2 rows: b = ty*2 + jb
    float acc[2][4] = {{0.f,0.f,0.f,0.f},{0.f,0.f,0.f,0.f}};

    for (int kc = 0; kc < 2048 / FKC; ++kc) {
        __syncthreads();
        for (int idx = tid; idx < B_ * (FKC / 4); idx += 256) {   // stage A
            int b2 = idx >> 5;
            int q  = idx & 31;
            int kg = kc * FKC + q * 4;
            const float* src = (kg < H_)
                ? (hs + ((size_t)t * 64 + b2) * H_ + kg)
                : (hs + ((size_t)(T_ - 1 - t) * 64 + B_ + b2) * H_ + (kg - H_));
            *(float4*)(&Al[b2][q * 4]) = *(const float4*)src;
        }
        for (int idx = tid; idx < FKC * 16; idx += 256) {         // stage B
            int kk = idx >> 4;
            int ci = idx & 15;
            *(float4*)(&Bl[kk][ci * 4]) =
                *(const float4*)(fco_w + (size_t)(kc * FKC + kk) * O_ + c0 + ci * 4);
        }
        __syncthreads();
        #pragma unroll 4
        for (int kl = 0; kl < FKC; ++kl) {
            float a0 = Al[ty * 2 + 0][kl];
            float a1 = Al[ty * 2 + 1][kl];
            float4 bv = *(const float4*)(&Bl[kl][tx * 4]);
            acc[0][0] += a0 * bv.x; acc[0][1] += a0 * bv.y;
            acc[0][2] += a0 * bv.z; acc[0][3] += a0 * bv.w;
            acc[1][0] += a1 * bv.x; acc[1][1] += a1 * bv.y;
            acc[1][2] += a1 * bv.z; acc[1][3] += a1 * bv.w;
        }
    }
    #pragma unroll
    for (int jb = 0; jb < 2; ++jb) {
        int b = ty * 2 + jb;
        #pragma unroll
        for (int jc = 0; jc < 4; ++jc) {
            int c = c0 + tx * 4 + jc;
            out[((size_t)t * B_ + b) * O_ + c] = acc[jb][jc] + fco_b[c];
        }
    }
}

extern "C" void kernel_launch(void* const* d_in, const int* in_sizes, int n_in,
                              void* d_out, int out_size, void* d_ws, size_t ws_size,
                              hipStream_t stream) {
    const float* x     = (const float*)d_in[0];
    const float* Wx    = (const float*)d_in[1];
    const float* bx    = (const float*)d_in[2];
    const float* Wh    = (const float*)d_in[3];
    const float* bh    = (const float*)d_in[4];
    const float* fco_w = (const float*)d_in[5];
    const float* fco_b = (const float*)d_in[6];
    float* out = (float*)d_out;
    float* ws  = (float*)d_ws;

    float* Wt    = ws + WT_OFF;
    float* bsum  = ws + BSUM_OFF;
    float* hzero = ws + HZ_OFF;
    float* hs    = ws + HS_OFF;

    prep_w<<<(NCOL * KTOT) / 256, 256, 0, stream>>>(Wx, Wh, Wt);
    prep_misc<<<(64 * H_ + 255) / 256 + 16, 256, 0, stream>>>(bx, bh, bsum, hzero);

    void* args[] = {(void*)&x, (void*)&Wt, (void*)&bsum, (void*)&hzero, (void*)&hs};
    hipLaunchCooperativeKernel((void*)recur, dim3(256), dim3(256), args, 0, stream);

    finalk<<<dim3(8, T_), 256, 0, stream>>>(hs, fco_w, fco_b, out);
}

// Round 5
// 11079.299 us; speedup vs baseline: 2.9233x; 2.9233x over previous
//
#include <hip/hip_runtime.h>
#include <hip/hip_cooperative_groups.h>

namespace cg = cooperative_groups;

typedef unsigned short u16;
typedef __attribute__((ext_vector_type(8))) short short8;
typedef __attribute__((ext_vector_type(4))) float f32x4;

#define T_ 256
#define B_ 32
#define F_ 512
#define H_ 1024
#define O_ 512
#define KT 1536    // H + F
#define NC 4096    // 4 gates * H, interleaved c = n*4 + g

// ---------------- ws byte offsets ----------------
#define WT_OFF  0                                   // Wt  bf16 [4096][1536]
#define XB_OFF  (WT_OFF + (size_t)NC * KT * 2)      // xb  bf16 [256][64][512]
#define FCO_OFF (XB_OFF + (size_t)256 * 64 * 512 * 2) // fcoT bf16 [512][2048]
#define BS_OFF  (FCO_OFF + (size_t)512 * 2048 * 2)  // bsum f32 [4096] (interleaved)
#define H0_OFF  (BS_OFF + (size_t)NC * 4)           // h0  bf16 [64][1024] zeros
#define HS_OFF  (H0_OFF + (size_t)64 * H_ * 2)      // hs  bf16 [256][64][1024]
// total ~65.2 MB

__device__ inline u16 f2bf(float f) {   // round-to-nearest-even f32 -> bf16
    unsigned u = __builtin_bit_cast(unsigned, f);
    u += 0x7FFFu + ((u >> 16) & 1u);
    return (u16)(u >> 16);
}

// Build Wt[c][k] bf16: c = (q*256+nn)*4 + g interleaved; k<1024 h-part, else x-part
__global__ void prep_wt(const float* __restrict__ Wx, const float* __restrict__ Wh,
                        u16* __restrict__ Wt) {
    int idx = blockIdx.x * 256 + threadIdx.x;       // over 4096*1536
    int c = idx / KT;
    int k = idx - c * KT;
    int g  = c & 3;
    int n  = c >> 2;          // 0..1023
    int q  = n >> 8;
    int nn = n & 255;
    const int   comp[4][4] = {{0,1,2,3},{1,0,3,2},{2,3,0,1},{3,2,1,0}};
    const float sgn [4][4] = {{1.f,-1.f,-1.f,-1.f},
                              {1.f, 1.f,-1.f, 1.f},
                              {1.f, 1.f, 1.f,-1.f},
                              {1.f,-1.f, 1.f, 1.f}};
    float v;
    if (k < H_) {
        int p = k >> 8, kk = k & 255;
        v = sgn[q][p] * Wh[((size_t)(g * 4 + comp[q][p]) * 256 + kk) * 256 + nn];
    } else {
        int k2 = k - H_;
        int p = k2 >> 7, kk = k2 & 127;
        v = sgn[q][p] * Wx[((size_t)(g * 4 + comp[q][p]) * 128 + kk) * 256 + nn];
    }
    Wt[idx] = f2bf(v);
}

// xb16[t][bb][f]: bb<32 -> x[t][bb][f], else x[255-t][bb-32][f]
__global__ void prep_xb(const float* __restrict__ x, u16* __restrict__ xb) {
    int idx = blockIdx.x * 256 + threadIdx.x;       // over 256*64*512
    int f  = idx & (F_ - 1);
    int r  = idx >> 9;
    int bb = r & 63;
    int t  = r >> 6;
    float v = (bb < B_) ? x[((size_t)t * B_ + bb) * F_ + f]
                        : x[((size_t)(T_ - 1 - t) * B_ + (bb - B_)) * F_ + f];
    xb[idx] = f2bf(v);
}

// fcoT[o][k] = fco_w[k][o]
__global__ void prep_fco(const float* __restrict__ fco_w, u16* __restrict__ fcoT) {
    int idx = blockIdx.x * 256 + threadIdx.x;       // over 512*2048
    int k = idx & 2047;
    int o = idx >> 11;
    fcoT[idx] = f2bf(fco_w[(size_t)k * O_ + o]);
}

// bsum interleaved + h0 zeros
__global__ void prep_bs(const float* __restrict__ bx, const float* __restrict__ bh,
                        float* __restrict__ bs, unsigned* __restrict__ h0w) {
    int idx = blockIdx.x * 256 + threadIdx.x;
    if (idx < NC) {
        int n = idx >> 2, g = idx & 3;
        bs[idx] = bx[g * H_ + n] + bh[g * H_ + n];
    }
    if (idx < 64 * H_ / 2) h0w[idx] = 0u;           // 32768 dwords of bf16 zeros
}

// ---------------------------------------------------------------------------
// Recurrence: 256 wgs x 512 threads (8 waves). wg owns 16 interleaved cols
// (n = wg*4..+4, 4 gates each). Wave w: m = w&3 (16 rows), ks = w>>2 (K half).
// A-frags direct from global hs/xb (bf16), B-frags direct from Wt (k-contig).
// Partials exchanged via LDS Cw, gate math on threads 0..255, grid.sync per t.
// ---------------------------------------------------------------------------
__global__ __launch_bounds__(512) void recur(
    const u16* __restrict__ Wt, const u16* __restrict__ xb,
    const float* __restrict__ bs, const u16* __restrict__ h0,
    u16* __restrict__ hs) {
    __shared__ float Cw[8][16][17];
    const int tid = threadIdx.x;
    const int wg  = blockIdx.x;
    const int l   = tid & 63;
    const int w   = tid >> 6;
    const int m   = w & 3;         // m-tile (16 rows)
    const int ks  = w >> 2;        // K half
    const int c0  = wg * 16;
    const int lr  = l & 15;        // A row-in-tile / B col-in-tile
    const int lq  = l >> 4;        // k sub-block
    const u16* wp = Wt + (size_t)(c0 + lr) * KT + lq * 8;   // B: 16B contig per lane

    // gate-math mapping (threads 0..255): (b, n_local j)
    const int gb = tid & 63;
    const int gj = (tid >> 6) & 3;
    float bsv[4];
    #pragma unroll
    for (int g = 0; g < 4; ++g) bsv[g] = bs[c0 + gj * 4 + g];

    cg::grid_group grid = cg::this_grid();
    float cst = 0.f;
    const u16* hprev = h0;

    for (int t = 0; t < T_; ++t) {
        f32x4 acc = {0.f, 0.f, 0.f, 0.f};
        const u16* hrow = hprev + (size_t)(m * 16 + lr) * H_ + lq * 8;
        const u16* xrow = xb + ((size_t)t * 64 + m * 16 + lr) * F_ + lq * 8;
        if (ks == 0) {
            for (int kk = 0; kk < 24; ++kk) {          // k = 0..768 (h)
                short8 a = *(const short8*)(hrow + kk * 32);
                short8 b = *(const short8*)(wp + kk * 32);
                acc = __builtin_amdgcn_mfma_f32_16x16x32_bf16(a, b, acc, 0, 0, 0);
            }
        } else {
            for (int kk = 0; kk < 8; ++kk) {           // k = 768..1024 (h)
                short8 a = *(const short8*)(hrow + 768 + kk * 32);
                short8 b = *(const short8*)(wp + 768 + kk * 32);
                acc = __builtin_amdgcn_mfma_f32_16x16x32_bf16(a, b, acc, 0, 0, 0);
            }
            for (int kk = 0; kk < 16; ++kk) {          // k = 1024..1536 (x)
                short8 a = *(const short8*)(xrow + kk * 32);
                short8 b = *(const short8*)(wp + H_ + kk * 32);
                acc = __builtin_amdgcn_mfma_f32_16x16x32_bf16(a, b, acc, 0, 0, 0);
            }
        }
        // C layout (m89-verified): col = l&15, row = (l>>4)*4 + r
        #pragma unroll
        for (int r = 0; r < 4; ++r) Cw[w][lq * 4 + r][lr] = acc[r];
        __syncthreads();
        if (tid < 256) {
            int mrow = gb >> 4, rr = gb & 15;
            float pf = Cw[mrow][rr][gj * 4 + 0] + Cw[4 + mrow][rr][gj * 4 + 0] + bsv[0];
            float pi = Cw[mrow][rr][gj * 4 + 1] + Cw[4 + mrow][rr][gj * 4 + 1] + bsv[1];
            float po = Cw[mrow][rr][gj * 4 + 2] + Cw[4 + mrow][rr][gj * 4 + 2] + bsv[2];
            float pa = Cw[mrow][rr][gj * 4 + 3] + Cw[4 + mrow][rr][gj * 4 + 3] + bsv[3];
            float ft = 1.f / (1.f + expf(-pf));
            float it = 1.f / (1.f + expf(-pi));
            float ot = 1.f / (1.f + expf(-po));
            cst = it * tanhf(pa) + ft * cst;
            float h = ot * tanhf(cst);
            hs[(size_t)t * (64 * H_) + (size_t)gb * H_ + (wg * 4 + gj)] = f2bf(h);
        }
        grid.sync();
        hprev = hs + (size_t)t * (64 * H_);
    }
}

// ---------------------------------------------------------------------------
// Final GEMM (MFMA): out[t][b][o] = [h_f | h_b] @ fco_w + fco_b
// grid (16, 256) x 256 thr; wave: m0 = (w&1)*16, c0 = bx*32 + (w>>1)*16; K=2048.
// ---------------------------------------------------------------------------
__global__ __launch_bounds__(256) void finalk(
    const u16* __restrict__ hs, const u16* __restrict__ fcoT,
    const float* __restrict__ fco_b, float* __restrict__ out) {
    const int tid = threadIdx.x;
    const int l = tid & 63, w = tid >> 6;
    const int t  = blockIdx.y;
    const int m0 = (w & 1) * 16;
    const int c0 = blockIdx.x * 32 + (w >> 1) * 16;
    const int lr = l & 15, lq = l >> 4;
    const u16* bp = fcoT + (size_t)(c0 + lr) * 2048 + lq * 8;
    const u16* af = hs + ((size_t)t * 64 + m0 + lr) * H_ + lq * 8;             // h_f
    const u16* ab = hs + ((size_t)(T_ - 1 - t) * 64 + B_ + m0 + lr) * H_ + lq * 8; // h_b
    f32x4 acc = {0.f, 0.f, 0.f, 0.f};
    for (int kk = 0; kk < 32; ++kk) {
        short8 a = *(const short8*)(af + kk * 32);
        short8 b = *(const short8*)(bp + kk * 32);
        acc = __builtin_amdgcn_mfma_f32_16x16x32_bf16(a, b, acc, 0, 0, 0);
    }
    for (int kk = 0; kk < 32; ++kk) {
        short8 a = *(const short8*)(ab + kk * 32);
        short8 b = *(const short8*)(bp + 1024 + kk * 32);
        acc = __builtin_amdgcn_mfma_f32_16x16x32_bf16(a, b, acc, 0, 0, 0);
    }
    const int col = c0 + lr;
    const float bb = fco_b[col];
    #pragma unroll
    for (int r = 0; r < 4; ++r) {
        int b = m0 + lq * 4 + r;
        out[((size_t)t * B_ + b) * O_ + col] = acc[r] + bb;
    }
}

extern "C" void kernel_launch(void* const* d_in, const int* in_sizes, int n_in,
                              void* d_out, int out_size, void* d_ws, size_t ws_size,
                              hipStream_t stream) {
    const float* x     = (const float*)d_in[0];
    const float* Wx    = (const float*)d_in[1];
    const float* bx    = (const float*)d_in[2];
    const float* Wh    = (const float*)d_in[3];
    const float* bh    = (const float*)d_in[4];
    const float* fco_w = (const float*)d_in[5];
    const float* fco_b = (const float*)d_in[6];
    float* out = (float*)d_out;
    char*  ws  = (char*)d_ws;

    u16*   Wt   = (u16*)(ws + WT_OFF);
    u16*   xb16 = (u16*)(ws + XB_OFF);
    u16*   fcoT = (u16*)(ws + FCO_OFF);
    float* bsum = (float*)(ws + BS_OFF);
    u16*   h0   = (u16*)(ws + H0_OFF);
    u16*   hs   = (u16*)(ws + HS_OFF);

    prep_wt<<<(NC * KT) / 256, 256, 0, stream>>>(Wx, Wh, Wt);
    prep_xb<<<(T_ * 64 * F_) / 256, 256, 0, stream>>>(x, xb16);
    prep_fco<<<(O_ * 2048) / 256, 256, 0, stream>>>(fco_w, fcoT);
    prep_bs<<<(64 * H_ / 2) / 256, 256, 0, stream>>>(bx, bh, bsum, (unsigned*)h0);

    void* args[] = {(void*)&Wt, (void*)&xb16, (void*)&bsum, (void*)&h0, (void*)&hs};
    hipLaunchCooperativeKernel((void*)recur, dim3(256), dim3(512), args, 0, stream);

    finalk<<<dim3(16, T_), 256, 0, stream>>>(hs, fcoT, fco_b, out);
}